// Round 1
// baseline (244.463 us; speedup 1.0000x reference)
//
#include <hip/hip_runtime.h>
#include <hip/hip_bf16.h>
#include <cstddef>

#define NUM_HEADS 4
#define EMBED 128
#define HEAD_DIM 32
#define CTXDIM 256
#define RANK 8
#define KW 7
#define SCALE 0.17677669529663687f

// ---------------------------------------------------------------------------
// Kernel 1: context scalars. 1 block, 256 threads = 4 waves, wave b handles
// batch b. cproj[b][8] = context[b] @ Blora ; alpha[b] = sigmoid(MLP).
// ---------------------------------------------------------------------------
__global__ __launch_bounds__(256) void ctx_kernel(
    const float* __restrict__ ctx, const float* __restrict__ Blora,
    const float* __restrict__ g1w, const float* __restrict__ g1b,
    const float* __restrict__ g2w, const float* __restrict__ g2b,
    float* __restrict__ cproj, float* __restrict__ alpha) {
  const int b = threadIdx.x >> 6;
  const int lane = threadIdx.x & 63;
  const float c0 = ctx[b * CTXDIM + lane];
  const float c1 = ctx[b * CTXDIM + 64 + lane];
  const float c2 = ctx[b * CTXDIM + 128 + lane];
  const float c3 = ctx[b * CTXDIM + 192 + lane];

#pragma unroll
  for (int r = 0; r < RANK; ++r) {
    float p = c0 * Blora[lane * RANK + r] + c1 * Blora[(64 + lane) * RANK + r] +
              c2 * Blora[(128 + lane) * RANK + r] + c3 * Blora[(192 + lane) * RANK + r];
#pragma unroll
    for (int s = 32; s; s >>= 1) p += __shfl_xor(p, s, 64);
    if (lane == 0) cproj[b * RANK + r] = p;
  }

  float gacc = 0.f;
#pragma unroll
  for (int h = 0; h < 16; ++h) {
    float p = c0 * g1w[h * CTXDIM + lane] + c1 * g1w[h * CTXDIM + 64 + lane] +
              c2 * g1w[h * CTXDIM + 128 + lane] + c3 * g1w[h * CTXDIM + 192 + lane];
#pragma unroll
    for (int s = 32; s; s >>= 1) p += __shfl_xor(p, s, 64);
    float hv = fmaxf(p + g1b[h], 0.f);
    gacc += hv * g2w[h];
  }
  if (lane == 0) {
    float a = gacc + g2b[0];
    alpha[b] = 1.f / (1.f + __expf(-a));
  }
}

// ---------------------------------------------------------------------------
// Kernel 2: u[n][r] = alpha[b] * cproj[b][r] * (x[n] @ A)[r].  Wave per pixel.
// ---------------------------------------------------------------------------
__global__ __launch_bounds__(256) void u_kernel(
    const float* __restrict__ x, const float* __restrict__ A,
    const float* __restrict__ cproj, const float* __restrict__ alpha,
    float* __restrict__ u) {
  const int wave = threadIdx.x >> 6;
  const int lane = threadIdx.x & 63;
  const int n = blockIdx.x * 4 + wave;
  const int b = n >> 12;  // 4096 pixels per batch
  const float x0 = x[(size_t)n * EMBED + lane];
  const float x1 = x[(size_t)n * EMBED + 64 + lane];
  const float al = alpha[b];
#pragma unroll
  for (int r = 0; r < RANK; ++r) {
    float p = x0 * A[lane * RANK + r] + x1 * A[(64 + lane) * RANK + r];
#pragma unroll
    for (int s = 32; s; s >>= 1) p += __shfl_xor(p, s, 64);
    if (lane == 0) u[(size_t)n * RANK + r] = al * cproj[b * RANK + r] * p;
  }
}

// ---------------------------------------------------------------------------
// Kernel 3/5: tiled fp32 GEMM.  C[m][n] = sum_k A[m][k]*B[n][k] + bias[n].
// A row stride = 128 (x or attnout); B row stride = 128 (Wqkv or Wproj).
// LORA: K extended to 136 with A-ext = u[m][0..8), B-ext = Vlora[n][0..8).
// BM=BN=64, BK=16, 256 threads, 4x4 microtile.
// ---------------------------------------------------------------------------
template <int NCHUNK, bool LORA>
__global__ __launch_bounds__(256) void gemm_kernel(
    const float* __restrict__ Am, const float* __restrict__ U,
    const float* __restrict__ Bm, const float* __restrict__ VL,
    const float* __restrict__ bias, float* __restrict__ Cm, int ldc) {
  __shared__ __align__(16) float As[16][68];
  __shared__ __align__(16) float Bs[16][68];

  const int m0 = blockIdx.x * 64;
  const int n0 = blockIdx.y * 64;
  const int t = threadIdx.x;
  const int lr = t >> 2;         // 0..63 : tile row for loads
  const int lk = (t & 3) * 4;    // 0,4,8,12 : k offset within chunk
  const int row0 = (t >> 4) * 4; // 0..60
  const int col0 = (t & 15) * 4; // 0..60

  float acc[4][4] = {{0.f}};

  for (int kc = 0; kc < NCHUNK; ++kc) {
    const int k = kc * 16 + lk;
    float4 av = make_float4(0.f, 0.f, 0.f, 0.f);
    float4 bv = make_float4(0.f, 0.f, 0.f, 0.f);
    if (!LORA || k < 128) {
      av = *(const float4*)&Am[(size_t)(m0 + lr) * 128 + k];
      bv = *(const float4*)&Bm[(size_t)(n0 + lr) * 128 + k];
    } else if (k < 136) {
      av = *(const float4*)&U[(size_t)(m0 + lr) * RANK + (k - 128)];
      bv = *(const float4*)&VL[(size_t)(n0 + lr) * RANK + (k - 128)];
    }
    __syncthreads();
    As[lk + 0][lr] = av.x; As[lk + 1][lr] = av.y;
    As[lk + 2][lr] = av.z; As[lk + 3][lr] = av.w;
    Bs[lk + 0][lr] = bv.x; Bs[lk + 1][lr] = bv.y;
    Bs[lk + 2][lr] = bv.z; Bs[lk + 3][lr] = bv.w;
    __syncthreads();
#pragma unroll
    for (int kk = 0; kk < 16; ++kk) {
      const float4 a = *(const float4*)&As[kk][row0];
      const float4 b = *(const float4*)&Bs[kk][col0];
      const float ar[4] = {a.x, a.y, a.z, a.w};
      const float br[4] = {b.x, b.y, b.z, b.w};
#pragma unroll
      for (int i = 0; i < 4; ++i)
#pragma unroll
        for (int j = 0; j < 4; ++j) acc[i][j] = fmaf(ar[i], br[j], acc[i][j]);
    }
  }

  const float4 bb = *(const float4*)&bias[n0 + col0];
#pragma unroll
  for (int i = 0; i < 4; ++i) {
    float4 o;
    o.x = acc[i][0] + bb.x; o.y = acc[i][1] + bb.y;
    o.z = acc[i][2] + bb.z; o.w = acc[i][3] + bb.w;
    *(float4*)&Cm[(size_t)(m0 + row0 + i) * ldc + n0 + col0] = o;
  }
}

// ---------------------------------------------------------------------------
// Kernel 4: neighborhood attention.  Thread = (pixel, head); wave = one image
// row (W=64) at fixed head, so row validity is wave-uniform.  Zero-padded
// positions participate in softmax with logit 0 (matches reference padding).
// qkv layout: [N][384] with j = which*128 + head*32 + d.  out: [N][128].
// ---------------------------------------------------------------------------
__global__ __launch_bounds__(256) void attn_kernel(
    const float* __restrict__ qkv, float* __restrict__ out) {
  const int head = threadIdx.x >> 6;
  const int j = threadIdx.x & 63;
  const int bi = blockIdx.x;      // b*64 + i
  const int i = bi & 63;
  const int base_pix = (bi >> 6) << 12;  // b*4096
  const int n = bi * 64 + j;

  float q[32];
  {
    const float* qp = qkv + (size_t)n * 384 + head * HEAD_DIM;
#pragma unroll
    for (int d8 = 0; d8 < 8; ++d8) {
      const float4 v = *(const float4*)(qp + d8 * 4);
      q[d8 * 4 + 0] = v.x; q[d8 * 4 + 1] = v.y;
      q[d8 * 4 + 2] = v.z; q[d8 * 4 + 3] = v.w;
    }
  }

  float l[49];
#pragma unroll
  for (int di = 0; di < KW; ++di) {
    const int ii = i + di - 3;
    const bool rv = (unsigned)ii < 64u;
#pragma unroll
    for (int dj = 0; dj < KW; ++dj) {
      const int jj = j + dj - 3;
      float acc = 0.f;
      if (rv && (unsigned)jj < 64u) {
        const float* kp =
            qkv + (size_t)(base_pix + ii * 64 + jj) * 384 + 128 + head * HEAD_DIM;
#pragma unroll
        for (int d8 = 0; d8 < 8; ++d8) {
          const float4 v = *(const float4*)(kp + d8 * 4);
          acc = fmaf(q[d8 * 4 + 0], v.x, acc);
          acc = fmaf(q[d8 * 4 + 1], v.y, acc);
          acc = fmaf(q[d8 * 4 + 2], v.z, acc);
          acc = fmaf(q[d8 * 4 + 3], v.w, acc);
        }
      }
      l[di * KW + dj] = acc * SCALE;  // OOB => exactly 0, still in softmax
    }
  }

  float mx = l[0];
#pragma unroll
  for (int t = 1; t < 49; ++t) mx = fmaxf(mx, l[t]);
  float s = 0.f;
#pragma unroll
  for (int t = 0; t < 49; ++t) {
    const float w = __expf(l[t] - mx);
    l[t] = w;
    s += w;
  }
  const float inv = 1.f / s;

  float o[32];
#pragma unroll
  for (int d = 0; d < 32; ++d) o[d] = 0.f;
#pragma unroll
  for (int di = 0; di < KW; ++di) {
    const int ii = i + di - 3;
    const bool rv = (unsigned)ii < 64u;
#pragma unroll
    for (int dj = 0; dj < KW; ++dj) {
      const int jj = j + dj - 3;
      if (rv && (unsigned)jj < 64u) {
        const float w = l[di * KW + dj];
        const float* vp =
            qkv + (size_t)(base_pix + ii * 64 + jj) * 384 + 256 + head * HEAD_DIM;
#pragma unroll
        for (int d8 = 0; d8 < 8; ++d8) {
          const float4 v = *(const float4*)(vp + d8 * 4);
          o[d8 * 4 + 0] = fmaf(w, v.x, o[d8 * 4 + 0]);
          o[d8 * 4 + 1] = fmaf(w, v.y, o[d8 * 4 + 1]);
          o[d8 * 4 + 2] = fmaf(w, v.z, o[d8 * 4 + 2]);
          o[d8 * 4 + 3] = fmaf(w, v.w, o[d8 * 4 + 3]);
        }
      }
    }
  }

  float* op = out + (size_t)n * EMBED + head * HEAD_DIM;
#pragma unroll
  for (int d8 = 0; d8 < 8; ++d8) {
    float4 v;
    v.x = o[d8 * 4 + 0] * inv; v.y = o[d8 * 4 + 1] * inv;
    v.z = o[d8 * 4 + 2] * inv; v.w = o[d8 * 4 + 3] * inv;
    *(float4*)(op + d8 * 4) = v;
  }
}

// ---------------------------------------------------------------------------
extern "C" void kernel_launch(void* const* d_in, const int* in_sizes, int n_in,
                              void* d_out, int out_size, void* d_ws, size_t ws_size,
                              hipStream_t stream) {
  const float* x     = (const float*)d_in[0];   // [4,64,64,128]
  const float* ctx   = (const float*)d_in[1];   // [4,256]
  const float* Wqkv  = (const float*)d_in[2];   // [384,128]
  const float* bqkv  = (const float*)d_in[3];   // [384]
  const float* A     = (const float*)d_in[4];   // [128,8]
  const float* Blora = (const float*)d_in[5];   // [256,8]
  const float* Vlora = (const float*)d_in[6];   // [384,8]
  const float* g1w   = (const float*)d_in[7];   // [16,256]
  const float* g1b   = (const float*)d_in[8];   // [16]
  const float* g2w   = (const float*)d_in[9];   // [1,16]
  const float* g2b   = (const float*)d_in[10];  // [1]
  const float* Wproj = (const float*)d_in[11];  // [128,128]
  const float* bproj = (const float*)d_in[12];  // [128]
  float* out = (float*)d_out;                   // [4,64,64,128]

  char* ws = (char*)d_ws;
  float* cproj   = (float*)(ws + 0);                     // 32 floats
  float* alpha   = (float*)(ws + 128);                   // 4 floats
  float* u       = (float*)(ws + 4096);                  // 16384*8   = 512 KB
  float* qkv     = (float*)(ws + (1u << 20));            // 16384*384 = 24 MB
  float* attnout = (float*)(ws + (1u << 20) + 25165824); // 16384*128 = 8 MB

  ctx_kernel<<<1, 256, 0, stream>>>(ctx, Blora, g1w, g1b, g2w, g2b, cproj, alpha);
  u_kernel<<<4096, 256, 0, stream>>>(x, A, cproj, alpha, u);
  gemm_kernel<9, true><<<dim3(256, 6), 256, 0, stream>>>(
      x, u, Wqkv, Vlora, bqkv, qkv, 384);
  attn_kernel<<<256, 256, 0, stream>>>(qkv, attnout);
  gemm_kernel<8, false><<<dim3(256, 2), 256, 0, stream>>>(
      attnout, nullptr, Wproj, nullptr, bproj, out, 128);
}

// Round 3
// 181.148 us; speedup vs baseline: 1.3495x; 1.3495x over previous
//
#include <hip/hip_runtime.h>
#include <hip/hip_bf16.h>
#include <cstddef>

#define NUM_HEADS 4
#define EMBED 128
#define HEAD_DIM 32
#define CTXDIM 256
#define RANK 8
#define KW 7
#define SCALE 0.17677669529663687f
#define NPIX 16384
#define PLANE (NPIX * 128)   // floats per qkv plane

// ---------------------------------------------------------------------------
// Kernel 1: context scalars. 1 block, 256 threads = 4 waves, wave b handles
// batch b. cproj[b][8] = context[b] @ Blora ; alpha[b] = sigmoid(MLP).
// ---------------------------------------------------------------------------
__global__ __launch_bounds__(256) void ctx_kernel(
    const float* __restrict__ ctx, const float* __restrict__ Blora,
    const float* __restrict__ g1w, const float* __restrict__ g1b,
    const float* __restrict__ g2w, const float* __restrict__ g2b,
    float* __restrict__ cproj, float* __restrict__ alpha) {
  const int b = threadIdx.x >> 6;
  const int lane = threadIdx.x & 63;
  const float c0 = ctx[b * CTXDIM + lane];
  const float c1 = ctx[b * CTXDIM + 64 + lane];
  const float c2 = ctx[b * CTXDIM + 128 + lane];
  const float c3 = ctx[b * CTXDIM + 192 + lane];

#pragma unroll
  for (int r = 0; r < RANK; ++r) {
    float p = c0 * Blora[lane * RANK + r] + c1 * Blora[(64 + lane) * RANK + r] +
              c2 * Blora[(128 + lane) * RANK + r] + c3 * Blora[(192 + lane) * RANK + r];
#pragma unroll
    for (int s = 32; s; s >>= 1) p += __shfl_xor(p, s, 64);
    if (lane == 0) cproj[b * RANK + r] = p;
  }

  float gacc = 0.f;
#pragma unroll
  for (int h = 0; h < 16; ++h) {
    float p = c0 * g1w[h * CTXDIM + lane] + c1 * g1w[h * CTXDIM + 64 + lane] +
              c2 * g1w[h * CTXDIM + 128 + lane] + c3 * g1w[h * CTXDIM + 192 + lane];
#pragma unroll
    for (int s = 32; s; s >>= 1) p += __shfl_xor(p, s, 64);
    float hv = fmaxf(p + g1b[h], 0.f);
    gacc += hv * g2w[h];
  }
  if (lane == 0) {
    float a = gacc + g2b[0];
    alpha[b] = 1.f / (1.f + __expf(-a));
  }
}

// ---------------------------------------------------------------------------
// Kernel 2: u[n][r] = alpha[b] * cproj[b][r] * (x[n] @ A)[r].  Wave per pixel.
// ---------------------------------------------------------------------------
__global__ __launch_bounds__(256) void u_kernel(
    const float* __restrict__ x, const float* __restrict__ A,
    const float* __restrict__ cproj, const float* __restrict__ alpha,
    float* __restrict__ u) {
  const int wave = threadIdx.x >> 6;
  const int lane = threadIdx.x & 63;
  const int n = blockIdx.x * 4 + wave;
  const int b = n >> 12;  // 4096 pixels per batch
  const float x0 = x[(size_t)n * EMBED + lane];
  const float x1 = x[(size_t)n * EMBED + 64 + lane];
  const float al = alpha[b];
#pragma unroll
  for (int r = 0; r < RANK; ++r) {
    float p = x0 * A[lane * RANK + r] + x1 * A[(64 + lane) * RANK + r];
#pragma unroll
    for (int s = 32; s; s >>= 1) p += __shfl_xor(p, s, 64);
    if (lane == 0) u[(size_t)n * RANK + r] = al * cproj[b * RANK + r] * p;
  }
}

// ---------------------------------------------------------------------------
// Kernel 3/5: tiled fp32 GEMM.  C = A @ B^T + bias, written PLANAR:
//   addr(m, n) = (n >> 7) * plane + m*128 + (n & 127)
// (block columns are 64-wide and n0 is 64-aligned, so (n>>7) is block-uniform;
//  plane=0 for the 128-col projection GEMM gives plain [m][n] layout).
// LORA: K extended to 136 with A-ext = u[m][0..8), B-ext = Vlora[n][0..8).
// BM=BN=64, BK=16, 256 threads, 4x4 microtile.
// ---------------------------------------------------------------------------
template <int NCHUNK, bool LORA>
__global__ __launch_bounds__(256) void gemm_kernel(
    const float* __restrict__ Am, const float* __restrict__ U,
    const float* __restrict__ Bm, const float* __restrict__ VL,
    const float* __restrict__ bias, float* __restrict__ Cm, int plane) {
  __shared__ __align__(16) float As[16][68];
  __shared__ __align__(16) float Bs[16][68];

  const int m0 = blockIdx.x * 64;
  const int n0 = blockIdx.y * 64;
  const int t = threadIdx.x;
  const int lr = t >> 2;         // 0..63 : tile row for loads
  const int lk = (t & 3) * 4;    // 0,4,8,12 : k offset within chunk
  const int row0 = (t >> 4) * 4; // 0..60
  const int col0 = (t & 15) * 4; // 0..60

  float acc[4][4] = {{0.f}};

  for (int kc = 0; kc < NCHUNK; ++kc) {
    const int k = kc * 16 + lk;
    float4 av = make_float4(0.f, 0.f, 0.f, 0.f);
    float4 bv = make_float4(0.f, 0.f, 0.f, 0.f);
    if (!LORA || k < 128) {
      av = *(const float4*)&Am[(size_t)(m0 + lr) * 128 + k];
      bv = *(const float4*)&Bm[(size_t)(n0 + lr) * 128 + k];
    } else if (k < 136) {
      av = *(const float4*)&U[(size_t)(m0 + lr) * RANK + (k - 128)];
      bv = *(const float4*)&VL[(size_t)(n0 + lr) * RANK + (k - 128)];
    }
    __syncthreads();
    As[lk + 0][lr] = av.x; As[lk + 1][lr] = av.y;
    As[lk + 2][lr] = av.z; As[lk + 3][lr] = av.w;
    Bs[lk + 0][lr] = bv.x; Bs[lk + 1][lr] = bv.y;
    Bs[lk + 2][lr] = bv.z; Bs[lk + 3][lr] = bv.w;
    __syncthreads();
#pragma unroll
    for (int kk = 0; kk < 16; ++kk) {
      const float4 a = *(const float4*)&As[kk][row0];
      const float4 b = *(const float4*)&Bs[kk][col0];
      const float ar[4] = {a.x, a.y, a.z, a.w};
      const float br[4] = {b.x, b.y, b.z, b.w};
#pragma unroll
      for (int i = 0; i < 4; ++i)
#pragma unroll
        for (int j = 0; j < 4; ++j) acc[i][j] = fmaf(ar[i], br[j], acc[i][j]);
    }
  }

  const int ncol = n0 + col0;
  const float4 bb = *(const float4*)&bias[ncol];
  float* cp = Cm + (size_t)(ncol >> 7) * plane + (ncol & 127);
#pragma unroll
  for (int i = 0; i < 4; ++i) {
    float4 o;
    o.x = acc[i][0] + bb.x; o.y = acc[i][1] + bb.y;
    o.z = acc[i][2] + bb.z; o.w = acc[i][3] + bb.w;
    *(float4*)&cp[(size_t)(m0 + row0 + i) * 128] = o;
  }
}

// ---------------------------------------------------------------------------
// Kernel 4: neighborhood attention, LDS-tiled, planar qkv [3][N][128].
// Block = (batch, 8x8 pixel tile, head). Stage 14x14 halo of k and v into LDS
// (zeros when OOB -> reproduces reference zero-pad softmax semantics exactly).
// 4 threads per pixel (dim quarters); logits reduced via 2 shuffles.
// `out` ALIASES the q plane: each thread reads exactly the 8 q-floats it
// later overwrites (k/v halo reads touch only k/v planes; q rows are read
// only by the block owning that tile+head slice) -> race-free, saves 8 MB ws.
// NOTE: no __restrict__ here, qkv and out alias.
// ---------------------------------------------------------------------------
#define HP 14           // halo width
#define NHALO 196       // 14*14
#define LSTRIDE 36
__global__ __launch_bounds__(256) void attn_kernel(
    const float* qkv, float* out) {
  __shared__ __align__(16) float ks[NHALO * LSTRIDE];
  __shared__ __align__(16) float vs[NHALO * LSTRIDE];

  const int bid = blockIdx.x;       // [0,1024)
  const int h = bid & 3;
  const int tj = (bid >> 2) & 7;
  const int ti = (bid >> 5) & 7;
  const int b = bid >> 8;
  const int t = threadIdx.x;

  const float* kpl = qkv + PLANE;
  const float* vpl = qkv + 2 * (size_t)PLANE;

  // ---- stage k/v halo (196 pixels x 32 floats each) ----
  const int i0 = ti * 8 - 3;
  const int j0 = tj * 8 - 3;
#pragma unroll
  for (int r = 0; r < 7; ++r) {
    const int f4 = t + r * 256;           // float4 index, [0,1568)
    if (f4 < NHALO * 8) {
      const int p = f4 >> 3;              // halo pixel
      const int d = (f4 & 7) * 4;         // dim offset
      const int hr = p / HP;
      const int hc = p - hr * HP;
      const int ii = i0 + hr;
      const int jj = j0 + hc;
      float4 kv = make_float4(0.f, 0.f, 0.f, 0.f);
      float4 vv = make_float4(0.f, 0.f, 0.f, 0.f);
      if ((unsigned)ii < 64u && (unsigned)jj < 64u) {
        const size_t gbase = (size_t)(b * 4096 + ii * 64 + jj) * 128 + h * HEAD_DIM + d;
        kv = *(const float4*)(kpl + gbase);
        vv = *(const float4*)(vpl + gbase);
      }
      *(float4*)&ks[p * LSTRIDE + d] = kv;
      *(float4*)&vs[p * LSTRIDE + d] = vv;
    }
  }
  __syncthreads();

  // ---- compute: 4 threads per pixel, dim quarters ----
  const int pix = t >> 2;        // 0..63
  const int qq = t & 3;          // dim quarter
  const int pi = pix >> 3;
  const int pj = pix & 7;
  const int n = b * 4096 + (ti * 8 + pi) * 64 + (tj * 8 + pj);
  const int dbase = qq * 8;

  float q[8];
  {
    const float* qp = qkv + (size_t)n * 128 + h * HEAD_DIM + dbase;
    const float4 a = *(const float4*)qp;
    const float4 c = *(const float4*)(qp + 4);
    q[0] = a.x; q[1] = a.y; q[2] = a.z; q[3] = a.w;
    q[4] = c.x; q[5] = c.y; q[6] = c.z; q[7] = c.w;
  }

  float l[49];
#pragma unroll
  for (int di = 0; di < KW; ++di) {
#pragma unroll
    for (int dj = 0; dj < KW; ++dj) {
      const int hp = (pi + di) * HP + (pj + dj);
      const float* kp = &ks[hp * LSTRIDE + dbase];
      const float4 a = *(const float4*)kp;
      const float4 c = *(const float4*)(kp + 4);
      float p = q[0] * a.x + q[1] * a.y + q[2] * a.z + q[3] * a.w +
                q[4] * c.x + q[5] * c.y + q[6] * c.z + q[7] * c.w;
      p += __shfl_xor(p, 1, 64);
      p += __shfl_xor(p, 2, 64);
      l[di * KW + dj] = p * SCALE;
    }
  }

  float mx = l[0];
#pragma unroll
  for (int s = 1; s < 49; ++s) mx = fmaxf(mx, l[s]);
  float sum = 0.f;
#pragma unroll
  for (int s = 0; s < 49; ++s) {
    const float w = __expf(l[s] - mx);
    l[s] = w;
    sum += w;
  }
  const float inv = 1.f / sum;

  float o[8] = {0.f, 0.f, 0.f, 0.f, 0.f, 0.f, 0.f, 0.f};
#pragma unroll
  for (int di = 0; di < KW; ++di) {
#pragma unroll
    for (int dj = 0; dj < KW; ++dj) {
      const int hp = (pi + di) * HP + (pj + dj);
      const float w = l[di * KW + dj];
      const float* vp = &vs[hp * LSTRIDE + dbase];
      const float4 a = *(const float4*)vp;
      const float4 c = *(const float4*)(vp + 4);
      o[0] = fmaf(w, a.x, o[0]); o[1] = fmaf(w, a.y, o[1]);
      o[2] = fmaf(w, a.z, o[2]); o[3] = fmaf(w, a.w, o[3]);
      o[4] = fmaf(w, c.x, o[4]); o[5] = fmaf(w, c.y, o[5]);
      o[6] = fmaf(w, c.z, o[6]); o[7] = fmaf(w, c.w, o[7]);
    }
  }

  float* op = out + (size_t)n * EMBED + h * HEAD_DIM + dbase;
  float4 r0, r1;
  r0.x = o[0] * inv; r0.y = o[1] * inv; r0.z = o[2] * inv; r0.w = o[3] * inv;
  r1.x = o[4] * inv; r1.y = o[5] * inv; r1.z = o[6] * inv; r1.w = o[7] * inv;
  *(float4*)op = r0;
  *(float4*)(op + 4) = r1;
}

// ---------------------------------------------------------------------------
// Workspace layout (25 MiB total; attn output aliases the q plane):
//   [0,128)            cproj
//   [128,144)          alpha
//   [4096, 528384)     u            (16384*8 fp32)
//   [1 MiB, 25 MiB)    qkv planar   [3][16384][128] fp32 (q/k/v planes, 8 MiB ea)
// ---------------------------------------------------------------------------
extern "C" void kernel_launch(void* const* d_in, const int* in_sizes, int n_in,
                              void* d_out, int out_size, void* d_ws, size_t ws_size,
                              hipStream_t stream) {
  const float* x     = (const float*)d_in[0];   // [4,64,64,128]
  const float* ctx   = (const float*)d_in[1];   // [4,256]
  const float* Wqkv  = (const float*)d_in[2];   // [384,128]
  const float* bqkv  = (const float*)d_in[3];   // [384]
  const float* A     = (const float*)d_in[4];   // [128,8]
  const float* Blora = (const float*)d_in[5];   // [256,8]
  const float* Vlora = (const float*)d_in[6];   // [384,8]
  const float* g1w   = (const float*)d_in[7];   // [16,256]
  const float* g1b   = (const float*)d_in[8];   // [16]
  const float* g2w   = (const float*)d_in[9];   // [1,16]
  const float* g2b   = (const float*)d_in[10];  // [1]
  const float* Wproj = (const float*)d_in[11];  // [128,128]
  const float* bproj = (const float*)d_in[12];  // [128]
  float* out = (float*)d_out;                   // [4,64,64,128]

  char* ws = (char*)d_ws;
  float* cproj = (float*)(ws + 0);              // 32 floats
  float* alpha = (float*)(ws + 128);            // 4 floats
  float* u     = (float*)(ws + 4096);           // 16384*8 = 512 KB
  float* qkv   = (float*)(ws + (1u << 20));     // 3 planes x 8 MB = 24 MB

  ctx_kernel<<<1, 256, 0, stream>>>(ctx, Blora, g1w, g1b, g2w, g2b, cproj, alpha);
  u_kernel<<<4096, 256, 0, stream>>>(x, A, cproj, alpha, u);
  gemm_kernel<9, true><<<dim3(256, 6), 256, 0, stream>>>(
      x, u, Wqkv, Vlora, bqkv, qkv, PLANE);
  attn_kernel<<<1024, 256, 0, stream>>>(qkv, qkv /* out aliases q plane */);
  gemm_kernel<8, false><<<dim3(256, 2), 256, 0, stream>>>(
      qkv, nullptr, Wproj, nullptr, bproj, out, 0);
}

// Round 4
// 149.404 us; speedup vs baseline: 1.6363x; 1.2125x over previous
//
#include <hip/hip_runtime.h>
#include <hip/hip_bf16.h>
#include <cstddef>

#define NUM_HEADS 4
#define EMBED 128
#define HEAD_DIM 32
#define CTXDIM 256
#define RANK 8
#define KW 7
#define SCALE 0.17677669529663687f
#define NPIX 16384
#define PLANE (NPIX * 128)   // floats per qkv plane

// ---------------------------------------------------------------------------
// Kernel 1: context scalars. 1 block, 256 threads = 4 waves, wave b handles
// batch b.  cal[b][r] = alpha_b * (context[b] @ Blora)[r]  (alpha pre-folded).
// ---------------------------------------------------------------------------
__global__ __launch_bounds__(256) void ctx_kernel(
    const float* __restrict__ ctx, const float* __restrict__ Blora,
    const float* __restrict__ g1w, const float* __restrict__ g1b,
    const float* __restrict__ g2w, const float* __restrict__ g2b,
    float* __restrict__ cal) {
  const int b = threadIdx.x >> 6;
  const int lane = threadIdx.x & 63;
  const float c0 = ctx[b * CTXDIM + lane];
  const float c1 = ctx[b * CTXDIM + 64 + lane];
  const float c2 = ctx[b * CTXDIM + 128 + lane];
  const float c3 = ctx[b * CTXDIM + 192 + lane];

  float cp[RANK];
#pragma unroll
  for (int r = 0; r < RANK; ++r) {
    float p = c0 * Blora[lane * RANK + r] + c1 * Blora[(64 + lane) * RANK + r] +
              c2 * Blora[(128 + lane) * RANK + r] + c3 * Blora[(192 + lane) * RANK + r];
#pragma unroll
    for (int s = 32; s; s >>= 1) p += __shfl_xor(p, s, 64);
    cp[r] = p;
  }

  float gacc = 0.f;
#pragma unroll
  for (int h = 0; h < 16; ++h) {
    float p = c0 * g1w[h * CTXDIM + lane] + c1 * g1w[h * CTXDIM + 64 + lane] +
              c2 * g1w[h * CTXDIM + 128 + lane] + c3 * g1w[h * CTXDIM + 192 + lane];
#pragma unroll
    for (int s = 32; s; s >>= 1) p += __shfl_xor(p, s, 64);
    float hv = fmaxf(p + g1b[h], 0.f);
    gacc += hv * g2w[h];
  }
  if (lane == 0) {
    const float alpha = 1.f / (1.f + __expf(-(gacc + g2b[0])));
#pragma unroll
    for (int r = 0; r < RANK; ++r) cal[b * RANK + r] = alpha * cp[r];
  }
}

// ---------------------------------------------------------------------------
// Kernel 2: weight fold.  W_eff[b][o][k] = Wqkv[o][k] +
//   sum_r Vlora[o][r] * cal[b][r] * A[k][r].
// Exact refactor of base + alpha*((xA)*c)@Vl^T into one per-batch GEMM weight.
// 768 blocks x 256 thr: block -> (b, 2 o-rows); thread -> (o, k).
// ---------------------------------------------------------------------------
__global__ __launch_bounds__(256) void fold_kernel(
    const float* __restrict__ Wqkv, const float* __restrict__ Vlora,
    const float* __restrict__ A, const float* __restrict__ cal,
    float* __restrict__ Weff) {
  const int bid = blockIdx.x;     // [0,768) = b*192 + ob
  const int b = bid / 192;
  const int ob = bid - b * 192;
  const int o = ob * 2 + (threadIdx.x >> 7);
  const int k = threadIdx.x & 127;

  const float4 a0 = *(const float4*)&A[k * RANK];
  const float4 a1 = *(const float4*)&A[k * RANK + 4];
  const float4 v0 = *(const float4*)&Vlora[o * RANK];
  const float4 v1 = *(const float4*)&Vlora[o * RANK + 4];
  const float4 c0 = *(const float4*)&cal[b * RANK];
  const float4 c1 = *(const float4*)&cal[b * RANK + 4];

  float d = a0.x * v0.x * c0.x;
  d = fmaf(a0.y * v0.y, c0.y, d);
  d = fmaf(a0.z * v0.z, c0.z, d);
  d = fmaf(a0.w * v0.w, c0.w, d);
  d = fmaf(a1.x * v1.x, c1.x, d);
  d = fmaf(a1.y * v1.y, c1.y, d);
  d = fmaf(a1.z * v1.z, c1.z, d);
  d = fmaf(a1.w * v1.w, c1.w, d);

  Weff[((size_t)b * 384 + o) * 128 + k] = Wqkv[o * 128 + k] + d;
}

// ---------------------------------------------------------------------------
// Kernel 3/5: tiled fp32 GEMM.  C = A @ B^T + bias, written PLANAR:
//   addr(m_g, n) = (n >> 7) * plane + m_g*128 + (n & 127)
// Batched over blockIdx.z: A rows offset by z*mstride, B by z*bstride.
// BM=BN=64, BK=16, 256 threads, 4x4 microtile, K=128 (8 chunks).
// ---------------------------------------------------------------------------
__global__ __launch_bounds__(256) void gemm_kernel(
    const float* __restrict__ Am, const float* __restrict__ Bm,
    const float* __restrict__ bias, float* __restrict__ Cm,
    int plane, int mstride, int bstride) {
  __shared__ __align__(16) float As[16][68];
  __shared__ __align__(16) float Bs[16][68];

  const int z = blockIdx.z;
  const int m0 = blockIdx.x * 64 + z * mstride;
  const int n0 = blockIdx.y * 64;
  const float* Bb = Bm + (size_t)z * bstride;
  const int t = threadIdx.x;
  const int lr = t >> 2;         // 0..63 : tile row for loads
  const int lk = (t & 3) * 4;    // 0,4,8,12 : k offset within chunk
  const int row0 = (t >> 4) * 4; // 0..60
  const int col0 = (t & 15) * 4; // 0..60

  float acc[4][4] = {{0.f}};

  for (int kc = 0; kc < 8; ++kc) {
    const int k = kc * 16 + lk;
    const float4 av = *(const float4*)&Am[(size_t)(m0 + lr) * 128 + k];
    const float4 bv = *(const float4*)&Bb[(size_t)(n0 + lr) * 128 + k];
    __syncthreads();
    As[lk + 0][lr] = av.x; As[lk + 1][lr] = av.y;
    As[lk + 2][lr] = av.z; As[lk + 3][lr] = av.w;
    Bs[lk + 0][lr] = bv.x; Bs[lk + 1][lr] = bv.y;
    Bs[lk + 2][lr] = bv.z; Bs[lk + 3][lr] = bv.w;
    __syncthreads();
#pragma unroll
    for (int kk = 0; kk < 16; ++kk) {
      const float4 a = *(const float4*)&As[kk][row0];
      const float4 b = *(const float4*)&Bs[kk][col0];
      const float ar[4] = {a.x, a.y, a.z, a.w};
      const float br[4] = {b.x, b.y, b.z, b.w};
#pragma unroll
      for (int i = 0; i < 4; ++i)
#pragma unroll
        for (int j = 0; j < 4; ++j) acc[i][j] = fmaf(ar[i], br[j], acc[i][j]);
    }
  }

  const int ncol = n0 + col0;
  const float4 bb = *(const float4*)&bias[ncol];
  float* cp = Cm + (size_t)(ncol >> 7) * plane + (ncol & 127);
#pragma unroll
  for (int i = 0; i < 4; ++i) {
    float4 o;
    o.x = acc[i][0] + bb.x; o.y = acc[i][1] + bb.y;
    o.z = acc[i][2] + bb.z; o.w = acc[i][3] + bb.w;
    *(float4*)&cp[(size_t)(m0 + row0 + i) * 128] = o;
  }
}

// ---------------------------------------------------------------------------
// Kernel 4: neighborhood attention, LDS-tiled, planar qkv [3][N][128].
// Block = (batch, 8x8 pixel tile, head). Stage 14x14 halo of k and v into LDS
// (zeros when OOB -> reproduces reference zero-pad softmax semantics exactly).
// 4 threads per pixel (dim quarters); logits reduced via 2 shuffles.
// `out` ALIASES the q plane: each thread reads exactly the 8 q-floats it
// later overwrites -> race-free.  No __restrict__ (qkv and out alias).
// ---------------------------------------------------------------------------
#define HP 14           // halo width
#define NHALO 196       // 14*14
#define LSTRIDE 36
__global__ __launch_bounds__(256) void attn_kernel(
    const float* qkv, float* out) {
  __shared__ __align__(16) float ks[NHALO * LSTRIDE];
  __shared__ __align__(16) float vs[NHALO * LSTRIDE];

  const int bid = blockIdx.x;       // [0,1024)
  const int h = bid & 3;
  const int tj = (bid >> 2) & 7;
  const int ti = (bid >> 5) & 7;
  const int b = bid >> 8;
  const int t = threadIdx.x;

  const float* kpl = qkv + PLANE;
  const float* vpl = qkv + 2 * (size_t)PLANE;

  // ---- stage k/v halo (196 pixels x 32 floats each) ----
  const int i0 = ti * 8 - 3;
  const int j0 = tj * 8 - 3;
#pragma unroll
  for (int r = 0; r < 7; ++r) {
    const int f4 = t + r * 256;           // float4 index, [0,1568)
    if (f4 < NHALO * 8) {
      const int p = f4 >> 3;              // halo pixel
      const int d = (f4 & 7) * 4;         // dim offset
      const int hr = p / HP;
      const int hc = p - hr * HP;
      const int ii = i0 + hr;
      const int jj = j0 + hc;
      float4 kv = make_float4(0.f, 0.f, 0.f, 0.f);
      float4 vv = make_float4(0.f, 0.f, 0.f, 0.f);
      if ((unsigned)ii < 64u && (unsigned)jj < 64u) {
        const size_t gbase = (size_t)(b * 4096 + ii * 64 + jj) * 128 + h * HEAD_DIM + d;
        kv = *(const float4*)(kpl + gbase);
        vv = *(const float4*)(vpl + gbase);
      }
      *(float4*)&ks[p * LSTRIDE + d] = kv;
      *(float4*)&vs[p * LSTRIDE + d] = vv;
    }
  }
  __syncthreads();

  // ---- compute: 4 threads per pixel, dim quarters ----
  const int pix = t >> 2;        // 0..63
  const int qq = t & 3;          // dim quarter
  const int pi = pix >> 3;
  const int pj = pix & 7;
  const int n = b * 4096 + (ti * 8 + pi) * 64 + (tj * 8 + pj);
  const int dbase = qq * 8;

  float q[8];
  {
    const float* qp = qkv + (size_t)n * 128 + h * HEAD_DIM + dbase;
    const float4 a = *(const float4*)qp;
    const float4 c = *(const float4*)(qp + 4);
    q[0] = a.x; q[1] = a.y; q[2] = a.z; q[3] = a.w;
    q[4] = c.x; q[5] = c.y; q[6] = c.z; q[7] = c.w;
  }

  float l[49];
#pragma unroll
  for (int di = 0; di < KW; ++di) {
#pragma unroll
    for (int dj = 0; dj < KW; ++dj) {
      const int hp = (pi + di) * HP + (pj + dj);
      const float* kp = &ks[hp * LSTRIDE + dbase];
      const float4 a = *(const float4*)kp;
      const float4 c = *(const float4*)(kp + 4);
      float p = q[0] * a.x + q[1] * a.y + q[2] * a.z + q[3] * a.w +
                q[4] * c.x + q[5] * c.y + q[6] * c.z + q[7] * c.w;
      p += __shfl_xor(p, 1, 64);
      p += __shfl_xor(p, 2, 64);
      l[di * KW + dj] = p * SCALE;
    }
  }

  float mx = l[0];
#pragma unroll
  for (int s = 1; s < 49; ++s) mx = fmaxf(mx, l[s]);
  float sum = 0.f;
#pragma unroll
  for (int s = 0; s < 49; ++s) {
    const float w = __expf(l[s] - mx);
    l[s] = w;
    sum += w;
  }
  const float inv = 1.f / sum;

  float o[8] = {0.f, 0.f, 0.f, 0.f, 0.f, 0.f, 0.f, 0.f};
#pragma unroll
  for (int di = 0; di < KW; ++di) {
#pragma unroll
    for (int dj = 0; dj < KW; ++dj) {
      const int hp = (pi + di) * HP + (pj + dj);
      const float w = l[di * KW + dj];
      const float* vp = &vs[hp * LSTRIDE + dbase];
      const float4 a = *(const float4*)vp;
      const float4 c = *(const float4*)(vp + 4);
      o[0] = fmaf(w, a.x, o[0]); o[1] = fmaf(w, a.y, o[1]);
      o[2] = fmaf(w, a.z, o[2]); o[3] = fmaf(w, a.w, o[3]);
      o[4] = fmaf(w, c.x, o[4]); o[5] = fmaf(w, c.y, o[5]);
      o[6] = fmaf(w, c.z, o[6]); o[7] = fmaf(w, c.w, o[7]);
    }
  }

  float* op = out + (size_t)n * EMBED + h * HEAD_DIM + dbase;
  float4 r0, r1;
  r0.x = o[0] * inv; r0.y = o[1] * inv; r0.z = o[2] * inv; r0.w = o[3] * inv;
  r1.x = o[4] * inv; r1.y = o[5] * inv; r1.z = o[6] * inv; r1.w = o[7] * inv;
  *(float4*)op = r0;
  *(float4*)(op + 4) = r1;
}

// ---------------------------------------------------------------------------
// Workspace layout (25 MiB; attn output aliases the q plane):
//   [0,128)            cal          (alpha*cproj, 32 floats)
//   [4096, 790528)     Weff         (4 x 384 x 128 fp32, 786 KB)
//   [1 MiB, 25 MiB)    qkv planar   [3][16384][128] fp32
// ---------------------------------------------------------------------------
extern "C" void kernel_launch(void* const* d_in, const int* in_sizes, int n_in,
                              void* d_out, int out_size, void* d_ws, size_t ws_size,
                              hipStream_t stream) {
  const float* x     = (const float*)d_in[0];   // [4,64,64,128]
  const float* ctx   = (const float*)d_in[1];   // [4,256]
  const float* Wqkv  = (const float*)d_in[2];   // [384,128]
  const float* bqkv  = (const float*)d_in[3];   // [384]
  const float* A     = (const float*)d_in[4];   // [128,8]
  const float* Blora = (const float*)d_in[5];   // [256,8]
  const float* Vlora = (const float*)d_in[6];   // [384,8]
  const float* g1w   = (const float*)d_in[7];   // [16,256]
  const float* g1b   = (const float*)d_in[8];   // [16]
  const float* g2w   = (const float*)d_in[9];   // [1,16]
  const float* g2b   = (const float*)d_in[10];  // [1]
  const float* Wproj = (const float*)d_in[11];  // [128,128]
  const float* bproj = (const float*)d_in[12];  // [128]
  float* out = (float*)d_out;                   // [4,64,64,128]

  char* ws = (char*)d_ws;
  float* cal  = (float*)(ws + 0);               // 32 floats
  float* Weff = (float*)(ws + 4096);            // 786 KB
  float* qkv  = (float*)(ws + (1u << 20));      // 3 planes x 8 MB = 24 MB

  ctx_kernel<<<1, 256, 0, stream>>>(ctx, Blora, g1w, g1b, g2w, g2b, cal);
  fold_kernel<<<768, 256, 0, stream>>>(Wqkv, Vlora, A, cal, Weff);
  gemm_kernel<<<dim3(64, 6, 4), 256, 0, stream>>>(
      x, Weff, bqkv, qkv, PLANE, 4096, 384 * 128);
  attn_kernel<<<1024, 256, 0, stream>>>(qkv, qkv /* out aliases q plane */);
  gemm_kernel<<<dim3(256, 2, 1), 256, 0, stream>>>(
      qkv, Wproj, bproj, out, 0, 0, 0);
}

// Round 5
// 141.027 us; speedup vs baseline: 1.7334x; 1.0594x over previous
//
#include <hip/hip_runtime.h>
#include <hip/hip_bf16.h>
#include <cstddef>

#define NUM_HEADS 4
#define EMBED 128
#define HEAD_DIM 32
#define CTXDIM 256
#define RANK 8
#define KW 7
#define SCALE 0.17677669529663687f
#define NPIX 16384
#define PLANE (NPIX * 128)   // floats per fp32 qkv plane

typedef _Float16 half8 __attribute__((ext_vector_type(8)));
typedef float floatx4 __attribute__((ext_vector_type(4)));

// ---------------------------------------------------------------------------
// Kernel 1: context scalars. 1 block; wave b handles batch b.
// cal[b][r] = alpha_b * (context[b] @ Blora)[r]  (alpha pre-folded).
// ---------------------------------------------------------------------------
__global__ __launch_bounds__(256) void ctx_kernel(
    const float* __restrict__ ctx, const float* __restrict__ Blora,
    const float* __restrict__ g1w, const float* __restrict__ g1b,
    const float* __restrict__ g2w, const float* __restrict__ g2b,
    float* __restrict__ cal) {
  const int b = threadIdx.x >> 6;
  const int lane = threadIdx.x & 63;
  const float c0 = ctx[b * CTXDIM + lane];
  const float c1 = ctx[b * CTXDIM + 64 + lane];
  const float c2 = ctx[b * CTXDIM + 128 + lane];
  const float c3 = ctx[b * CTXDIM + 192 + lane];

  float cp[RANK];
#pragma unroll
  for (int r = 0; r < RANK; ++r) {
    float p = c0 * Blora[lane * RANK + r] + c1 * Blora[(64 + lane) * RANK + r] +
              c2 * Blora[(128 + lane) * RANK + r] + c3 * Blora[(192 + lane) * RANK + r];
#pragma unroll
    for (int s = 32; s; s >>= 1) p += __shfl_xor(p, s, 64);
    cp[r] = p;
  }

  float gacc = 0.f;
#pragma unroll
  for (int h = 0; h < 16; ++h) {
    float p = c0 * g1w[h * CTXDIM + lane] + c1 * g1w[h * CTXDIM + 64 + lane] +
              c2 * g1w[h * CTXDIM + 128 + lane] + c3 * g1w[h * CTXDIM + 192 + lane];
#pragma unroll
    for (int s = 32; s; s >>= 1) p += __shfl_xor(p, s, 64);
    float hv = fmaxf(p + g1b[h], 0.f);
    gacc += hv * g2w[h];
  }
  if (lane == 0) {
    const float alpha = 1.f / (1.f + __expf(-(gacc + g2b[0])));
#pragma unroll
    for (int r = 0; r < RANK; ++r) cal[b * RANK + r] = alpha * cp[r];
  }
}

// ---------------------------------------------------------------------------
// Kernel 2: weight fold -> fp16.  Weff[b][o][k] = fp16(Wqkv[o][k] +
//   sum_r Vlora[o][r]*cal[b][r]*A[k][r]).  Blocks [768,832) convert Wproj.
// ---------------------------------------------------------------------------
__global__ __launch_bounds__(256) void fold_kernel(
    const float* __restrict__ Wqkv, const float* __restrict__ Vlora,
    const float* __restrict__ A, const float* __restrict__ cal,
    const float* __restrict__ Wproj,
    _Float16* __restrict__ Weff16, _Float16* __restrict__ Wp16) {
  const int bid = blockIdx.x;
  if (bid >= 768) {   // Wproj fp32 -> fp16 (16384 elems over 64 blocks)
    const int i = (bid - 768) * 256 + threadIdx.x;
    Wp16[i] = (_Float16)Wproj[i];
    return;
  }
  const int b = bid / 192;
  const int ob = bid - b * 192;
  const int o = ob * 2 + (threadIdx.x >> 7);
  const int k = threadIdx.x & 127;

  const float4 a0 = *(const float4*)&A[k * RANK];
  const float4 a1 = *(const float4*)&A[k * RANK + 4];
  const float4 v0 = *(const float4*)&Vlora[o * RANK];
  const float4 v1 = *(const float4*)&Vlora[o * RANK + 4];
  const float4 c0 = *(const float4*)&cal[b * RANK];
  const float4 c1 = *(const float4*)&cal[b * RANK + 4];

  float d = a0.x * v0.x * c0.x;
  d = fmaf(a0.y * v0.y, c0.y, d);
  d = fmaf(a0.z * v0.z, c0.z, d);
  d = fmaf(a0.w * v0.w, c0.w, d);
  d = fmaf(a1.x * v1.x, c1.x, d);
  d = fmaf(a1.y * v1.y, c1.y, d);
  d = fmaf(a1.z * v1.z, c1.z, d);
  d = fmaf(a1.w * v1.w, c1.w, d);

  Weff16[((size_t)b * 384 + o) * 128 + k] = (_Float16)(Wqkv[o * 128 + k] + d);
}

// ---------------------------------------------------------------------------
// Kernel 3: x fp32 -> fp16.  8 elems/thread, 1024 blocks.
// ---------------------------------------------------------------------------
__global__ __launch_bounds__(256) void xcvt_kernel(
    const float* __restrict__ x, _Float16* __restrict__ x16) {
  const size_t i = ((size_t)blockIdx.x * 256 + threadIdx.x) * 8;
  const float4 a = *(const float4*)(x + i);
  const float4 b = *(const float4*)(x + i + 4);
  half8 o;
  o[0] = (_Float16)a.x; o[1] = (_Float16)a.y;
  o[2] = (_Float16)a.z; o[3] = (_Float16)a.w;
  o[4] = (_Float16)b.x; o[5] = (_Float16)b.y;
  o[6] = (_Float16)b.z; o[7] = (_Float16)b.w;
  *(half8*)(x16 + i) = o;
}

// ---------------------------------------------------------------------------
// Kernel 4/6: fp16 MFMA GEMM.  C[m][n] = A[m][:] . B[n][:] + bias[n], K=128.
// No LDS: fragments loaded straight from global (B tile is L1-resident;
// A reads are 16 rows x 64 B segments per inst, L1/L2-served).
// Fragment maps (m89/m118-verified): A[m=lane&15][k=quad*8+j],
// B[k][n=lane&15] (= row n of B matrix), D: col=lane&15, row=quad*4+reg.
// Block 256 thr = 4 waves; wave w -> rows m0+16w..+15, all 64 cols (4 tiles).
// C written planar: addr = (n>>7)*plane + m*128 + (n&127).
// Batched via blockIdx.z: A rows += z*mstride, B += z*bstride.
// ---------------------------------------------------------------------------
__global__ __launch_bounds__(256) void gemm16_kernel(
    const _Float16* __restrict__ A16, const _Float16* __restrict__ B16,
    const float* __restrict__ bias, float* __restrict__ C,
    int plane, int mstride, int bstride) {
  const int z = blockIdx.z;
  const int m0 = blockIdx.x * 64 + z * mstride;
  const int n0 = blockIdx.y * 64;
  const int lane = threadIdx.x & 63;
  const int w = threadIdx.x >> 6;
  const int r = lane & 15;
  const int quad = lane >> 4;

  const _Float16* ap = A16 + (size_t)(m0 + w * 16 + r) * 128 + quad * 8;
  const _Float16* bp = B16 + (size_t)z * bstride + (size_t)(n0 + r) * 128 + quad * 8;

  floatx4 acc0 = {0.f, 0.f, 0.f, 0.f};
  floatx4 acc1 = {0.f, 0.f, 0.f, 0.f};
  floatx4 acc2 = {0.f, 0.f, 0.f, 0.f};
  floatx4 acc3 = {0.f, 0.f, 0.f, 0.f};

#pragma unroll
  for (int kc = 0; kc < 4; ++kc) {
    const half8 a = *(const half8*)(ap + kc * 32);
    const half8 b0 = *(const half8*)(bp + kc * 32);
    const half8 b1 = *(const half8*)(bp + 16 * 128 + kc * 32);
    const half8 b2 = *(const half8*)(bp + 32 * 128 + kc * 32);
    const half8 b3 = *(const half8*)(bp + 48 * 128 + kc * 32);
    acc0 = __builtin_amdgcn_mfma_f32_16x16x32_f16(a, b0, acc0, 0, 0, 0);
    acc1 = __builtin_amdgcn_mfma_f32_16x16x32_f16(a, b1, acc1, 0, 0, 0);
    acc2 = __builtin_amdgcn_mfma_f32_16x16x32_f16(a, b2, acc2, 0, 0, 0);
    acc3 = __builtin_amdgcn_mfma_f32_16x16x32_f16(a, b3, acc3, 0, 0, 0);
  }

  const int mbase = m0 + w * 16 + quad * 4;
  floatx4 accs[4] = {acc0, acc1, acc2, acc3};
#pragma unroll
  for (int nt = 0; nt < 4; ++nt) {
    const int n = n0 + nt * 16 + r;
    const float bv = bias[n];
    float* cp = C + (size_t)(n >> 7) * plane + (size_t)mbase * 128 + (n & 127);
#pragma unroll
    for (int reg = 0; reg < 4; ++reg)
      cp[(size_t)reg * 128] = accs[nt][reg] + bv;
  }
}

// ---------------------------------------------------------------------------
// Kernel 5: neighborhood attention, LDS-tiled, planar fp32 qkv [3][N][128].
// Block = (batch, 8x8 pixel tile, head); 14x14 k/v halo staged in LDS with
// zero-fill for OOB (matches reference zero-pad softmax semantics exactly).
// 4 threads/pixel (dim quarters), 2-shuffle logit reduce.
// Output written as fp16 [N][128] (feeds the MFMA projection GEMM).
// ---------------------------------------------------------------------------
#define HP 14
#define NHALO 196
#define LSTRIDE 36
__global__ __launch_bounds__(256) void attn_kernel(
    const float* __restrict__ qkv, _Float16* __restrict__ out16) {
  __shared__ __align__(16) float ks[NHALO * LSTRIDE];
  __shared__ __align__(16) float vs[NHALO * LSTRIDE];

  const int bid = blockIdx.x;       // [0,1024)
  const int h = bid & 3;
  const int tj = (bid >> 2) & 7;
  const int ti = (bid >> 5) & 7;
  const int b = bid >> 8;
  const int t = threadIdx.x;

  const float* kpl = qkv + PLANE;
  const float* vpl = qkv + 2 * (size_t)PLANE;

  const int i0 = ti * 8 - 3;
  const int j0 = tj * 8 - 3;
#pragma unroll
  for (int r = 0; r < 7; ++r) {
    const int f4 = t + r * 256;
    if (f4 < NHALO * 8) {
      const int p = f4 >> 3;
      const int d = (f4 & 7) * 4;
      const int hr = p / HP;
      const int hc = p - hr * HP;
      const int ii = i0 + hr;
      const int jj = j0 + hc;
      float4 kv = make_float4(0.f, 0.f, 0.f, 0.f);
      float4 vv = make_float4(0.f, 0.f, 0.f, 0.f);
      if ((unsigned)ii < 64u && (unsigned)jj < 64u) {
        const size_t gbase = (size_t)(b * 4096 + ii * 64 + jj) * 128 + h * HEAD_DIM + d;
        kv = *(const float4*)(kpl + gbase);
        vv = *(const float4*)(vpl + gbase);
      }
      *(float4*)&ks[p * LSTRIDE + d] = kv;
      *(float4*)&vs[p * LSTRIDE + d] = vv;
    }
  }
  __syncthreads();

  const int pix = t >> 2;
  const int qq = t & 3;
  const int pi = pix >> 3;
  const int pj = pix & 7;
  const int n = b * 4096 + (ti * 8 + pi) * 64 + (tj * 8 + pj);
  const int dbase = qq * 8;

  float q[8];
  {
    const float* qp = qkv + (size_t)n * 128 + h * HEAD_DIM + dbase;
    const float4 a = *(const float4*)qp;
    const float4 c = *(const float4*)(qp + 4);
    q[0] = a.x; q[1] = a.y; q[2] = a.z; q[3] = a.w;
    q[4] = c.x; q[5] = c.y; q[6] = c.z; q[7] = c.w;
  }

  float l[49];
#pragma unroll
  for (int di = 0; di < KW; ++di) {
#pragma unroll
    for (int dj = 0; dj < KW; ++dj) {
      const int hp = (pi + di) * HP + (pj + dj);
      const float* kp = &ks[hp * LSTRIDE + dbase];
      const float4 a = *(const float4*)kp;
      const float4 c = *(const float4*)(kp + 4);
      float p = q[0] * a.x + q[1] * a.y + q[2] * a.z + q[3] * a.w +
                q[4] * c.x + q[5] * c.y + q[6] * c.z + q[7] * c.w;
      p += __shfl_xor(p, 1, 64);
      p += __shfl_xor(p, 2, 64);
      l[di * KW + dj] = p * SCALE;
    }
  }

  float mx = l[0];
#pragma unroll
  for (int s = 1; s < 49; ++s) mx = fmaxf(mx, l[s]);
  float sum = 0.f;
#pragma unroll
  for (int s = 0; s < 49; ++s) {
    const float w = __expf(l[s] - mx);
    l[s] = w;
    sum += w;
  }
  const float inv = 1.f / sum;

  float o[8] = {0.f, 0.f, 0.f, 0.f, 0.f, 0.f, 0.f, 0.f};
#pragma unroll
  for (int di = 0; di < KW; ++di) {
#pragma unroll
    for (int dj = 0; dj < KW; ++dj) {
      const int hp = (pi + di) * HP + (pj + dj);
      const float w = l[di * KW + dj];
      const float* vp = &vs[hp * LSTRIDE + dbase];
      const float4 a = *(const float4*)vp;
      const float4 c = *(const float4*)(vp + 4);
      o[0] = fmaf(w, a.x, o[0]); o[1] = fmaf(w, a.y, o[1]);
      o[2] = fmaf(w, a.z, o[2]); o[3] = fmaf(w, a.w, o[3]);
      o[4] = fmaf(w, c.x, o[4]); o[5] = fmaf(w, c.y, o[5]);
      o[6] = fmaf(w, c.z, o[6]); o[7] = fmaf(w, c.w, o[7]);
    }
  }

  half8 ov;
  ov[0] = (_Float16)(o[0] * inv); ov[1] = (_Float16)(o[1] * inv);
  ov[2] = (_Float16)(o[2] * inv); ov[3] = (_Float16)(o[3] * inv);
  ov[4] = (_Float16)(o[4] * inv); ov[5] = (_Float16)(o[5] * inv);
  ov[6] = (_Float16)(o[6] * inv); ov[7] = (_Float16)(o[7] * inv);
  *(half8*)(out16 + (size_t)n * 128 + h * HEAD_DIM + dbase) = ov;
}

// ---------------------------------------------------------------------------
// Workspace (29 MB total):
//   [0,128)          cal
//   [4 KB, 388 KB)   Weff16  [4][384][128] fp16
//   [448 KB, 480 KB) Wp16    [128][128] fp16
//   [1 MB, 5 MB)     x16     [16384][128] fp16  (reused as attnout16 — x16 is
//                            dead after gemm1, attn doesn't read it)
//   [5 MB, 29 MB)    qkv     [3][16384][128] fp32 planar
// ---------------------------------------------------------------------------
extern "C" void kernel_launch(void* const* d_in, const int* in_sizes, int n_in,
                              void* d_out, int out_size, void* d_ws, size_t ws_size,
                              hipStream_t stream) {
  const float* x     = (const float*)d_in[0];
  const float* ctx   = (const float*)d_in[1];
  const float* Wqkv  = (const float*)d_in[2];
  const float* bqkv  = (const float*)d_in[3];
  const float* A     = (const float*)d_in[4];
  const float* Blora = (const float*)d_in[5];
  const float* Vlora = (const float*)d_in[6];
  const float* g1w   = (const float*)d_in[7];
  const float* g1b   = (const float*)d_in[8];
  const float* g2w   = (const float*)d_in[9];
  const float* g2b   = (const float*)d_in[10];
  const float* Wproj = (const float*)d_in[11];
  const float* bproj = (const float*)d_in[12];
  float* out = (float*)d_out;

  char* ws = (char*)d_ws;
  float*     cal    = (float*)(ws + 0);
  _Float16*  Weff16 = (_Float16*)(ws + (4u << 10));
  _Float16*  Wp16   = (_Float16*)(ws + (448u << 10));
  _Float16*  x16    = (_Float16*)(ws + (1u << 20));   // doubles as attnout16
  float*     qkv    = (float*)(ws + (5u << 20));

  ctx_kernel<<<1, 256, 0, stream>>>(ctx, Blora, g1w, g1b, g2w, g2b, cal);
  fold_kernel<<<832, 256, 0, stream>>>(Wqkv, Vlora, A, cal, Wproj, Weff16, Wp16);
  xcvt_kernel<<<1024, 256, 0, stream>>>(x, x16);
  gemm16_kernel<<<dim3(64, 6, 4), 256, 0, stream>>>(
      x16, Weff16, bqkv, qkv, PLANE, 4096, 384 * 128);
  attn_kernel<<<1024, 256, 0, stream>>>(qkv, x16 /* reuse as attnout16 */);
  gemm16_kernel<<<dim3(256, 2, 1), 256, 0, stream>>>(
      x16, Wp16, bproj, out, 0, 0, 0);
}